// Round 1
// baseline (715.774 us; speedup 1.0000x reference)
//
#include <hip/hip_runtime.h>

#define DIN 128
#define H1  64
#define H2  32

// ---- degree count: deg[dst[e]] += 1 over the E real edges ----
__global__ void k_deg(const int* __restrict__ dst, float* __restrict__ deg, int E) {
    int i = blockIdx.x * blockDim.x + threadIdx.x;
    int stride = gridDim.x * blockDim.x;
    for (; i < E; i += stride) atomicAdd(&deg[dst[i]], 1.0f);
}

// ---- dinv[n] = rsqrt(deg[n] + 1)  (the +1 is the self-loop) ----
__global__ void k_dinv(float* __restrict__ deg, int N) {
    int i = blockIdx.x * blockDim.x + threadIdx.x;
    if (i < N) deg[i] = rsqrtf(deg[i] + 1.0f);
}

// ---- t1 = x @ W1 ; agg1 = t1 * dinv^2 (self-loop init, fused epilogue) ----
__global__ __launch_bounds__(256) void k_gemm1(const float* __restrict__ x,
        const float* __restrict__ W1, const float* __restrict__ dinv,
        float* __restrict__ t1, float* __restrict__ agg1, int N) {
    __shared__ float sW[DIN * H1];   // 32 KB
    __shared__ float sx[4][DIN];     // 2 KB
    int tid = threadIdx.x;
    for (int i = tid; i < DIN * H1; i += 256) sW[i] = W1[i];
    int row0 = blockIdx.x * 4;
    for (int i = tid; i < 4 * DIN; i += 256) {
        int r = i >> 7, c = i & (DIN - 1);
        int row = row0 + r;
        sx[r][c] = (row < N) ? x[(size_t)row * DIN + c] : 0.f;
    }
    __syncthreads();
    int j = tid & (H1 - 1);   // output col
    int r = tid >> 6;         // row within tile
    int row = row0 + r;
    if (row < N) {
        float acc = 0.f;
#pragma unroll
        for (int k = 0; k < DIN; ++k) acc = fmaf(sx[r][k], sW[k * H1 + j], acc);
        float d = dinv[row];
        t1[(size_t)row * H1 + j]   = acc;
        agg1[(size_t)row * H1 + j] = acc * d * d;
    }
}

// ---- t2 = relu(agg1) @ W2 ; out = t2 * dinv^2 (fused epilogue) ----
__global__ __launch_bounds__(256) void k_gemm2(const float* __restrict__ agg1,
        const float* __restrict__ W2, const float* __restrict__ dinv,
        float* __restrict__ t2, float* __restrict__ out, int N) {
    __shared__ float sW[H1 * H2];    // 8 KB
    __shared__ float sx[8][H1];      // 2 KB
    int tid = threadIdx.x;
    for (int i = tid; i < H1 * H2; i += 256) sW[i] = W2[i];
    int row0 = blockIdx.x * 8;
    for (int i = tid; i < 8 * H1; i += 256) {
        int r = i >> 6, c = i & (H1 - 1);
        int row = row0 + r;
        sx[r][c] = (row < N) ? fmaxf(agg1[(size_t)row * H1 + c], 0.f) : 0.f;
    }
    __syncthreads();
    int j = tid & (H2 - 1);
    int r = tid >> 5;
    int row = row0 + r;
    if (row < N) {
        float acc = 0.f;
#pragma unroll
        for (int k = 0; k < H1; ++k) acc = fmaf(sx[r][k], sW[k * H2 + j], acc);
        float d = dinv[row];
        t2[(size_t)row * H2 + j]  = acc;
        out[(size_t)row * H2 + j] = acc * d * d;
    }
}

// ---- edge scatter: agg[dst] += t[src] * dinv[src]*dinv[dst], one thread/feature ----
template <int LOGF>
__global__ void k_scatter(const int* __restrict__ src, const int* __restrict__ dst,
                          const float* __restrict__ dinv, const float* __restrict__ t,
                          float* __restrict__ agg, int E) {
    const int F = 1 << LOGF;
    long long gid = (long long)blockIdx.x * blockDim.x + threadIdx.x;
    int e = (int)(gid >> LOGF);
    int j = (int)(gid & (F - 1));
    if (e < E) {
        int s = src[e], d = dst[e];
        float norm = dinv[s] * dinv[d];
        float val = t[((size_t)s << LOGF) + j] * norm;
        atomicAdd(&agg[((size_t)d << LOGF) + j], val);
    }
}

extern "C" void kernel_launch(void* const* d_in, const int* in_sizes, int n_in,
                              void* d_out, int out_size, void* d_ws, size_t ws_size,
                              hipStream_t stream) {
    const float* x  = (const float*)d_in[0];
    const int*   ei = (const int*)d_in[1];   // int32 (JAX x64 disabled)
    const float* W1 = (const float*)d_in[2];
    const float* W2 = (const float*)d_in[3];

    const int N = in_sizes[0] / DIN;   // 100000
    const int E = in_sizes[1] / 2;     // 1600000
    const int* src = ei;
    const int* dst = ei + E;

    float* dinv = (float*)d_ws;                 // N floats (holds deg first)
    float* t1   = dinv + N;                     // N*64
    float* agg1 = t1 + (size_t)N * H1;          // N*64
    float* t2   = t1;                           // reuse t1 region after ReLU
    float* out  = (float*)d_out;                // N*32

    // degree -> dinv
    hipMemsetAsync(dinv, 0, (size_t)N * sizeof(float), stream);
    k_deg<<<2048, 256, 0, stream>>>(dst, dinv, E);
    k_dinv<<<(N + 255) / 256, 256, 0, stream>>>(dinv, N);

    // layer 1
    k_gemm1<<<(N + 3) / 4, 256, 0, stream>>>(x, W1, dinv, t1, agg1, N);
    {
        long long threads = (long long)E << 6;            // E * 64
        int blocks = (int)((threads + 255) / 256);
        k_scatter<6><<<blocks, 256, 0, stream>>>(src, dst, dinv, t1, agg1, E);
    }

    // layer 2 (ReLU fused into gemm2 load)
    k_gemm2<<<(N + 7) / 8, 256, 0, stream>>>(agg1, W2, dinv, t2, out, N);
    {
        long long threads = (long long)E << 5;            // E * 32
        int blocks = (int)((threads + 255) / 256);
        k_scatter<5><<<blocks, 256, 0, stream>>>(src, dst, dinv, t2, out, E);
    }
}

// Round 2
// 529.408 us; speedup vs baseline: 1.3520x; 1.3520x over previous
//
#include <hip/hip_runtime.h>

#define DIN 128
#define H1  64
#define H2  32

// ---- degree count (int) ----
__global__ void k_deg(const int* __restrict__ dst, int* __restrict__ degi, int E) {
    int i = blockIdx.x * blockDim.x + threadIdx.x;
    int stride = gridDim.x * blockDim.x;
    for (; i < E; i += stride) atomicAdd(&degi[dst[i]], 1);
}

// ---- dinv[n] = rsqrt(deg[n] + 1) ----
__global__ void k_dinv(const int* __restrict__ degi, float* __restrict__ dinv, int N) {
    int i = blockIdx.x * blockDim.x + threadIdx.x;
    if (i < N) dinv[i] = rsqrtf((float)degi[i] + 1.0f);
}

// ---- scan step 1: per-block (1024 elems) exclusive scan + block totals ----
__global__ __launch_bounds__(256) void k_scan1(const int* __restrict__ degi,
        int* __restrict__ rowptr, int* __restrict__ partial, int N) {
    int tid = threadIdx.x;
    int base = blockIdx.x * 1024 + tid * 4;
    int v0 = (base + 0 < N) ? degi[base + 0] : 0;
    int v1 = (base + 1 < N) ? degi[base + 1] : 0;
    int v2 = (base + 2 < N) ? degi[base + 2] : 0;
    int v3 = (base + 3 < N) ? degi[base + 3] : 0;
    int sum = v0 + v1 + v2 + v3;
    int lane = tid & 63, wid = tid >> 6;
    int x = sum;
#pragma unroll
    for (int off = 1; off < 64; off <<= 1) {
        int y = __shfl_up(x, off, 64);
        if (lane >= off) x += y;
    }
    __shared__ int wsum[4];
    if (lane == 63) wsum[wid] = x;
    __syncthreads();
    int wbase = 0;
    for (int w = 0; w < wid; ++w) wbase += wsum[w];
    int excl = wbase + x - sum;
    if (base + 0 < N) rowptr[base + 0] = excl;
    if (base + 1 < N) rowptr[base + 1] = excl + v0;
    if (base + 2 < N) rowptr[base + 2] = excl + v0 + v1;
    if (base + 3 < N) rowptr[base + 3] = excl + v0 + v1 + v2;
    if (tid == 0) partial[blockIdx.x] = wsum[0] + wsum[1] + wsum[2] + wsum[3];
}

// ---- scan step 2: serial exclusive scan of the ~98 block totals ----
__global__ void k_scan2(int* __restrict__ partial, int nb) {
    int run = 0;
    for (int i = 0; i < nb; ++i) { int v = partial[i]; partial[i] = run; run += v; }
}

// ---- scan step 3: add block offsets; init cursor = rowptr ----
__global__ void k_scan3(int* __restrict__ rowptr, int* __restrict__ cursor,
                        const int* __restrict__ partial, int N) {
    int i = blockIdx.x * blockDim.x + threadIdx.x;
    if (i < N) { int v = rowptr[i] + partial[i >> 10]; rowptr[i] = v; cursor[i] = v; }
}

// ---- CSR fill: csr_src[cursor[dst]++] = src ----
__global__ void k_fill(const int* __restrict__ src, const int* __restrict__ dst,
                       int* __restrict__ cursor, int* __restrict__ csr_src, int E) {
    int i = blockIdx.x * blockDim.x + threadIdx.x;
    int stride = gridDim.x * blockDim.x;
    for (; i < E; i += stride) {
        int d = dst[i];
        int pos = atomicAdd(&cursor[d], 1);
        csr_src[pos] = src[i];
    }
}

// ---- t1' = (x @ W1) * dinv (rowwise), 8 rows/block ----
__global__ __launch_bounds__(256) void k_gemm1(const float* __restrict__ x,
        const float* __restrict__ W1, const float* __restrict__ dinv,
        float* __restrict__ t1p, int N) {
    __shared__ float sW[DIN * H1];   // 32 KB
    __shared__ float sx[8][DIN];     // 4 KB
    int tid = threadIdx.x;
    for (int i = tid; i < DIN * H1; i += 256) sW[i] = W1[i];
    int row0 = blockIdx.x * 8;
    for (int i = tid; i < 8 * DIN; i += 256) {
        int r = i >> 7, c = i & 127;
        int row = row0 + r;
        sx[r][c] = (row < N) ? x[(size_t)row * DIN + c] : 0.f;
    }
    __syncthreads();
    int j = tid & 63, r = tid >> 6;
    float a0 = 0.f, a1 = 0.f;
#pragma unroll
    for (int k = 0; k < DIN; ++k) {
        float w = sW[k * H1 + j];
        a0 = fmaf(sx[r][k], w, a0);
        a1 = fmaf(sx[r + 4][k], w, a1);
    }
    int row = row0 + r;
    if (row < N) t1p[(size_t)row * H1 + j] = a0 * dinv[row];
    row = row0 + r + 4;
    if (row < N) t1p[(size_t)row * H1 + j] = a1 * dinv[row];
}

// ---- t2' = (relu(agg1) @ W2) * dinv (rowwise), 8 rows/block ----
__global__ __launch_bounds__(256) void k_gemm2(const float* __restrict__ agg1,
        const float* __restrict__ W2, const float* __restrict__ dinv,
        float* __restrict__ t2p, int N) {
    __shared__ float sW[H1 * H2];    // 8 KB
    __shared__ float sx[8][H1];      // 2 KB
    int tid = threadIdx.x;
    for (int i = tid; i < H1 * H2; i += 256) sW[i] = W2[i];
    int row0 = blockIdx.x * 8;
    for (int i = tid; i < 8 * H1; i += 256) {
        int r = i >> 6, c = i & 63;
        int row = row0 + r;
        sx[r][c] = (row < N) ? fmaxf(agg1[(size_t)row * H1 + c], 0.f) : 0.f;
    }
    __syncthreads();
    int j = tid & 31, r = tid >> 5;
    float a = 0.f;
#pragma unroll
    for (int k = 0; k < H1; ++k) a = fmaf(sx[r][k], sW[k * H2 + j], a);
    int row = row0 + r;
    if (row < N) t2p[(size_t)row * H2 + j] = a * dinv[row];
}

// ---- pull aggregation: out[n] = dinv[n] * (t'[n] + sum_{s in CSR(n)} t'[s]) ----
template <int LOGF>
__global__ __launch_bounds__(256) void k_agg(const int* __restrict__ rowptr,
        const int* __restrict__ degi, const int* __restrict__ csr_src,
        const float* __restrict__ dinv, const float* __restrict__ tp,
        float* __restrict__ out, int N) {
    const int F = 1 << LOGF;
    int local = threadIdx.x >> LOGF;
    int j = threadIdx.x & (F - 1);
    int n = blockIdx.x * (256 >> LOGF) + local;
    if (n >= N) return;
    int start = rowptr[n];
    int deg = degi[n];
    float acc = tp[((size_t)n << LOGF) + j];   // self-loop term (t' already * dinv)
    int k = 0;
    for (; k + 4 <= deg; k += 4) {
        int s0 = csr_src[start + k + 0];
        int s1 = csr_src[start + k + 1];
        int s2 = csr_src[start + k + 2];
        int s3 = csr_src[start + k + 3];
        acc += tp[((size_t)s0 << LOGF) + j];
        acc += tp[((size_t)s1 << LOGF) + j];
        acc += tp[((size_t)s2 << LOGF) + j];
        acc += tp[((size_t)s3 << LOGF) + j];
    }
    for (; k < deg; ++k) {
        int s = csr_src[start + k];
        acc += tp[((size_t)s << LOGF) + j];
    }
    out[((size_t)n << LOGF) + j] = acc * dinv[n];
}

extern "C" void kernel_launch(void* const* d_in, const int* in_sizes, int n_in,
                              void* d_out, int out_size, void* d_ws, size_t ws_size,
                              hipStream_t stream) {
    const float* x  = (const float*)d_in[0];
    const int*   ei = (const int*)d_in[1];
    const float* W1 = (const float*)d_in[2];
    const float* W2 = (const float*)d_in[3];

    const int N = in_sizes[0] / DIN;   // 100000
    const int E = in_sizes[1] / 2;     // 1600000
    const int* src = ei;
    const int* dst = ei + E;

    // workspace layout (all 4-byte elems)
    float* dinv   = (float*)d_ws;                    // N
    int*   degi   = (int*)(dinv + N);                // N
    int*   rowptr = degi + N;                        // N
    int*   cursor = rowptr + N;                      // N
    int*   partial= cursor + N;                      // 256
    int*   csr_src= partial + 256;                   // E
    float* t1p    = (float*)(csr_src + E);           // N*64
    float* agg1   = t1p + (size_t)N * H1;            // N*64
    float* t2p    = t1p;                             // reuse after agg1 built
    float* out    = (float*)d_out;                   // N*32

    const int nb = (N + 1023) / 1024;                // scan blocks (98)

    // --- CSR build ---
    hipMemsetAsync(degi, 0, (size_t)N * sizeof(int), stream);
    k_deg<<<2048, 256, 0, stream>>>(dst, degi, E);
    k_dinv<<<(N + 255) / 256, 256, 0, stream>>>(degi, dinv, N);
    k_scan1<<<nb, 256, 0, stream>>>(degi, rowptr, partial, N);
    k_scan2<<<1, 1, 0, stream>>>(partial, nb);
    k_scan3<<<(N + 255) / 256, 256, 0, stream>>>(rowptr, cursor, partial, N);
    k_fill<<<2048, 256, 0, stream>>>(src, dst, cursor, csr_src, E);

    // --- layer 1 ---
    k_gemm1<<<(N + 7) / 8, 256, 0, stream>>>(x, W1, dinv, t1p, N);
    k_agg<6><<<(N + 3) / 4, 256, 0, stream>>>(rowptr, degi, csr_src, dinv, t1p, agg1, N);

    // --- layer 2 ---
    k_gemm2<<<(N + 7) / 8, 256, 0, stream>>>(agg1, W2, dinv, t2p, N);
    k_agg<5><<<(N + 7) / 8, 256, 0, stream>>>(rowptr, degi, csr_src, dinv, t2p, out, N);
}

// Round 3
// 374.602 us; speedup vs baseline: 1.9108x; 1.4133x over previous
//
#include <hip/hip_runtime.h>

#define DIN 128
#define H1  64
#define H2  32

// ---- degree count (int) ----
__global__ void k_deg(const int* __restrict__ dst, int* __restrict__ degi, int E) {
    int i = blockIdx.x * blockDim.x + threadIdx.x;
    int stride = gridDim.x * blockDim.x;
    for (; i < E; i += stride) atomicAdd(&degi[dst[i]], 1);
}

// ---- dinv[n] = rsqrt(deg[n] + 1) ----
__global__ void k_dinv(const int* __restrict__ degi, float* __restrict__ dinv, int N) {
    int i = blockIdx.x * blockDim.x + threadIdx.x;
    if (i < N) dinv[i] = rsqrtf((float)degi[i] + 1.0f);
}

// ---- scan step 1: per-block (1024 elems) exclusive scan + block totals ----
__global__ __launch_bounds__(256) void k_scan1(const int* __restrict__ degi,
        int* __restrict__ rowptr, int* __restrict__ partial, int N) {
    int tid = threadIdx.x;
    int base = blockIdx.x * 1024 + tid * 4;
    int v0 = (base + 0 < N) ? degi[base + 0] : 0;
    int v1 = (base + 1 < N) ? degi[base + 1] : 0;
    int v2 = (base + 2 < N) ? degi[base + 2] : 0;
    int v3 = (base + 3 < N) ? degi[base + 3] : 0;
    int sum = v0 + v1 + v2 + v3;
    int lane = tid & 63, wid = tid >> 6;
    int x = sum;
#pragma unroll
    for (int off = 1; off < 64; off <<= 1) {
        int y = __shfl_up(x, off, 64);
        if (lane >= off) x += y;
    }
    __shared__ int wsum[4];
    if (lane == 63) wsum[wid] = x;
    __syncthreads();
    int wbase = 0;
    for (int w = 0; w < wid; ++w) wbase += wsum[w];
    int excl = wbase + x - sum;
    if (base + 0 < N) rowptr[base + 0] = excl;
    if (base + 1 < N) rowptr[base + 1] = excl + v0;
    if (base + 2 < N) rowptr[base + 2] = excl + v0 + v1;
    if (base + 3 < N) rowptr[base + 3] = excl + v0 + v1 + v2;
    if (tid == 0) partial[blockIdx.x] = wsum[0] + wsum[1] + wsum[2] + wsum[3];
}

// ---- scan step 2: one-block exclusive scan of the block totals (nb <= 128) ----
__global__ __launch_bounds__(128) void k_scan2(int* __restrict__ partial, int nb) {
    int tid = threadIdx.x;
    int v = (tid < nb) ? partial[tid] : 0;
    __shared__ int tmp[128];
    tmp[tid] = v;
    __syncthreads();
    for (int off = 1; off < 128; off <<= 1) {
        int y = (tid >= off) ? tmp[tid - off] : 0;
        __syncthreads();
        tmp[tid] += y;
        __syncthreads();
    }
    if (tid < nb) partial[tid] = tmp[tid] - v;   // exclusive
}

// ---- scan step 3: add block offsets; init cursor = rowptr ----
__global__ void k_scan3(int* __restrict__ rowptr, int* __restrict__ cursor,
                        const int* __restrict__ partial, int N) {
    int i = blockIdx.x * blockDim.x + threadIdx.x;
    if (i < N) { int v = rowptr[i] + partial[i >> 10]; rowptr[i] = v; cursor[i] = v; }
}

// ---- CSR fill: csr_src[cursor[dst]++] = src ----
__global__ void k_fill(const int* __restrict__ src, const int* __restrict__ dst,
                       int* __restrict__ cursor, int* __restrict__ csr_src, int E) {
    int i = blockIdx.x * blockDim.x + threadIdx.x;
    int stride = gridDim.x * blockDim.x;
    for (; i < E; i += stride) {
        int d = dst[i];
        int pos = atomicAdd(&cursor[d], 1);
        csr_src[pos] = src[i];
    }
}

// ---- register-blocked GEMM: out = (op(in) @ W) * dinv rowwise ----
// 64-row tile per block; thread computes RPT rows x 4 cols; all LDS reads b128.
template <int K, int COLS, bool RELU>
__global__ __launch_bounds__(256) void k_gemm(const float* __restrict__ in,
        const float* __restrict__ W, const float* __restrict__ dinv,
        float* __restrict__ outp, int N) {
    constexpr int TX  = COLS / 4;      // threads along cols (16 or 8)
    constexpr int TY  = 256 / TX;      // threads along rows (16 or 32)
    constexpr int RPT = 64 / TY;       // rows per thread (4 or 2)
    constexpr int XS  = K + 4;         // padded LDS row stride (floats)
    __shared__ float sW[K * COLS];
    __shared__ float sx[64 * XS];
    int tid = threadIdx.x;
    // stage W once (coalesced float4)
    for (int i = tid; i < K * COLS / 4; i += 256)
        *(float4*)&sW[i * 4] = *(const float4*)&W[i * 4];
    int row0 = blockIdx.x * 64;
    // stage 64-row x tile (coalesced float4, zero-pad OOB, optional ReLU)
    constexpr int F4R = K / 4;         // float4 per row
    for (int i = tid; i < 64 * F4R; i += 256) {
        int r = i / F4R, c4 = i % F4R;
        int row = row0 + r;
        float4 v = make_float4(0.f, 0.f, 0.f, 0.f);
        if (row < N) {
            v = *(const float4*)&in[(size_t)row * K + c4 * 4];
            if (RELU) {
                v.x = fmaxf(v.x, 0.f); v.y = fmaxf(v.y, 0.f);
                v.z = fmaxf(v.z, 0.f); v.w = fmaxf(v.w, 0.f);
            }
        }
        *(float4*)&sx[r * XS + c4 * 4] = v;
    }
    __syncthreads();
    int tx = tid % TX, ty = tid / TX;
    int c0 = tx * 4, r0 = ty * RPT;
    float acc[RPT][4] = {};
#pragma unroll 2
    for (int kk = 0; kk < K / 4; ++kk) {
        float b[4][4];
#pragma unroll
        for (int u = 0; u < 4; ++u)
            *(float4*)b[u] = *(const float4*)&sW[(kk * 4 + u) * COLS + c0];
        float a[RPT][4];
#pragma unroll
        for (int r = 0; r < RPT; ++r)
            *(float4*)a[r] = *(const float4*)&sx[(r0 + r) * XS + kk * 4];
#pragma unroll
        for (int r = 0; r < RPT; ++r)
#pragma unroll
            for (int u = 0; u < 4; ++u)
#pragma unroll
                for (int c = 0; c < 4; ++c)
                    acc[r][c] = fmaf(a[r][u], b[u][c], acc[r][c]);
    }
#pragma unroll
    for (int r = 0; r < RPT; ++r) {
        int row = row0 + r0 + r;
        if (row < N) {
            float d = dinv[row];
            float4 v = make_float4(acc[r][0] * d, acc[r][1] * d,
                                   acc[r][2] * d, acc[r][3] * d);
            *(float4*)&outp[(size_t)row * COLS + c0] = v;
        }
    }
}

// ---- pull aggregation: out[n] = dinv[n] * (t'[n] + sum_{s in CSR(n)} t'[s]) ----
template <int LOGF>
__global__ __launch_bounds__(256) void k_agg(const int* __restrict__ rowptr,
        const int* __restrict__ degi, const int* __restrict__ csr_src,
        const float* __restrict__ dinv, const float* __restrict__ tp,
        float* __restrict__ out, int N) {
    const int F = 1 << LOGF;
    int local = threadIdx.x >> LOGF;
    int j = threadIdx.x & (F - 1);
    int n = blockIdx.x * (256 >> LOGF) + local;
    if (n >= N) return;
    int start = rowptr[n];
    int deg = degi[n];
    float acc = tp[((size_t)n << LOGF) + j];   // self-loop term (t' already * dinv)
    int k = 0;
    for (; k + 4 <= deg; k += 4) {
        int s0 = csr_src[start + k + 0];
        int s1 = csr_src[start + k + 1];
        int s2 = csr_src[start + k + 2];
        int s3 = csr_src[start + k + 3];
        acc += tp[((size_t)s0 << LOGF) + j];
        acc += tp[((size_t)s1 << LOGF) + j];
        acc += tp[((size_t)s2 << LOGF) + j];
        acc += tp[((size_t)s3 << LOGF) + j];
    }
    for (; k < deg; ++k) {
        int s = csr_src[start + k];
        acc += tp[((size_t)s << LOGF) + j];
    }
    out[((size_t)n << LOGF) + j] = acc * dinv[n];
}

extern "C" void kernel_launch(void* const* d_in, const int* in_sizes, int n_in,
                              void* d_out, int out_size, void* d_ws, size_t ws_size,
                              hipStream_t stream) {
    const float* x  = (const float*)d_in[0];
    const int*   ei = (const int*)d_in[1];
    const float* W1 = (const float*)d_in[2];
    const float* W2 = (const float*)d_in[3];

    const int N = in_sizes[0] / DIN;   // 100000
    const int E = in_sizes[1] / 2;     // 1600000
    const int* src = ei;
    const int* dst = ei + E;

    // workspace layout (all 4-byte elems)
    float* dinv    = (float*)d_ws;                   // N
    int*   degi    = (int*)(dinv + N);               // N
    int*   rowptr  = degi + N;                       // N
    int*   cursor  = rowptr + N;                     // N
    int*   partial = cursor + N;                     // 256
    int*   csr_src = partial + 256;                  // E
    float* t1p     = (float*)(csr_src + E);          // N*64
    float* agg1    = t1p + (size_t)N * H1;           // N*64
    float* t2p     = t1p;                            // reuse after agg1 built
    float* out     = (float*)d_out;                  // N*32

    const int nb = (N + 1023) / 1024;                // scan blocks (98)

    // --- CSR build ---
    hipMemsetAsync(degi, 0, (size_t)N * sizeof(int), stream);
    k_deg<<<2048, 256, 0, stream>>>(dst, degi, E);
    k_dinv<<<(N + 255) / 256, 256, 0, stream>>>(degi, dinv, N);
    k_scan1<<<nb, 256, 0, stream>>>(degi, rowptr, partial, N);
    k_scan2<<<1, 128, 0, stream>>>(partial, nb);
    k_scan3<<<(N + 255) / 256, 256, 0, stream>>>(rowptr, cursor, partial, N);
    k_fill<<<2048, 256, 0, stream>>>(src, dst, cursor, csr_src, E);

    const int ntile = (N + 63) / 64;                 // 1563

    // --- layer 1 ---
    k_gemm<DIN, H1, false><<<ntile, 256, 0, stream>>>(x, W1, dinv, t1p, N);
    k_agg<6><<<(N + 3) / 4, 256, 0, stream>>>(rowptr, degi, csr_src, dinv, t1p, agg1, N);

    // --- layer 2 ---
    k_gemm<H1, H2, true><<<ntile, 256, 0, stream>>>(agg1, W2, dinv, t2p, N);
    k_agg<5><<<(N + 7) / 8, 256, 0, stream>>>(rowptr, degi, csr_src, dinv, t2p, out, N);
}